// Round 14
// baseline (110.147 us; speedup 1.0000x reference)
//
#include <hip/hip_runtime.h>

typedef __bf16 bf16x8 __attribute__((ext_vector_type(8)));
typedef float  f32x4  __attribute__((ext_vector_type(4)));
typedef unsigned short u16;
typedef unsigned int   u32;

__device__ __forceinline__ float b2f(u16 u) {
    u32 x = ((u32)u) << 16;
    return __builtin_bit_cast(float, x);
}
__device__ __forceinline__ u16 f2b(float f) {
    u32 x = __builtin_bit_cast(u32, f);
    x += 0x7fffu + ((x >> 16) & 1u);   // RNE
    return (u16)(x >> 16);
}

// ---------------------------------------------------------------------------
// Kernel 1: convert x, [wq;wk;wv], wo  f32 -> bf16  (vectorized x4)
// ---------------------------------------------------------------------------
__global__ void convert_kernel(const float* __restrict__ x, const float* __restrict__ wq,
                               const float* __restrict__ wk, const float* __restrict__ wv,
                               const float* __restrict__ wo,
                               u16* __restrict__ xb, u16* __restrict__ wcat, u16* __restrict__ wob)
{
    long i4 = (long)blockIdx.x * 256 + threadIdx.x;   // 0..3670015
    long e = i4 * 4;
    const float* src; u16* dst;
    if (e < 4194304) { src = x + e; dst = xb + e; }
    else if (e < 10485760) {
        long j = e - 4194304;
        dst = wcat + j;
        if (j < 4194304)      src = wq + j;
        else if (j < 5242880) src = wk + (j - 4194304);
        else                  src = wv + (j - 5242880);
    } else {
        long j = e - 10485760;
        src = wo + j; dst = wob + j;
    }
    float4 v = *(const float4*)src;
    uint2 pk;
    pk.x = (u32)f2b(v.x) | ((u32)f2b(v.y) << 16);
    pk.y = (u32)f2b(v.z) | ((u32)f2b(v.w) << 16);
    *(uint2*)dst = pk;
}

// ---------------------------------------------------------------------------
// Kernel 2a: bf16 GEMM for QKV projection (MODE 1 epilogue).
// 128x128 tile, BK=64, 256 threads = 4 waves (2M x 2N), wave = 64x64 out.
// LDS reads/FLOP 0.67x of the 64x32-wave shape; 64KB LDS -> 2 blocks/CU.
// Counted-vmcnt 2-buffer: { STAGE(next); vmcnt(8); s_barrier; COMPUTE; s_barrier }.
// ---------------------------------------------------------------------------
template<int MODE>
__global__ __launch_bounds__(256) void gemm_bt128_kernel(
    const u16* __restrict__ A, const u16* __restrict__ B,
    void* __restrict__ Cout, int M, int N, int K,
    u16* __restrict__ qb, u16* __restrict__ c1kv, const float* __restrict__ fc)
{
    __shared__ u16 As[2][8192];   // 128 x 64
    __shared__ u16 Bs[2][8192];   // 128 x 64
    const int tid  = threadIdx.x;
    const int lane = tid & 63;
    const int wave = tid >> 6;
    const int waveM = wave >> 1, waveN = wave & 1;
    const int tm = blockIdx.y * 128;
    const int tn = blockIdx.x * 128;

    f32x4 acc[4][4];
#pragma unroll
    for (int i = 0; i < 4; ++i)
#pragma unroll
        for (int j = 0; j < 4; ++j) acc[i][j] = f32x4{0.f, 0.f, 0.f, 0.f};

    const int frow = lane & 15;
    const int fk   = (lane >> 4) * 8;

    auto STAGE = [&](int buf, int kt) {
#pragma unroll
        for (int c = 0; c < 4; ++c) {          // A: 1024 16B chunks
            int idx = c * 256 + tid;
            int row = idx >> 3;                // 0..127
            int blk = (idx & 7) ^ (row & 7);   // swizzled source chunk
            const u16* srcA = A + (size_t)(tm + row) * K + kt + blk * 8;
            u16* dstA = &As[buf][(size_t)(c * 256 + wave * 64) * 8];
            __builtin_amdgcn_global_load_lds((const __attribute__((address_space(1))) void*)srcA,
                                             (__attribute__((address_space(3))) void*)dstA, 16, 0, 0);
        }
#pragma unroll
        for (int c = 0; c < 4; ++c) {          // B: 1024 16B chunks
            int idx = c * 256 + tid;
            int row = idx >> 3;                // 0..127
            int blk = (idx & 7) ^ (row & 7);
            const u16* srcB = B + (size_t)(tn + row) * K + kt + blk * 8;
            u16* dstB = &Bs[buf][(size_t)(c * 256 + wave * 64) * 8];
            __builtin_amdgcn_global_load_lds((const __attribute__((address_space(1))) void*)srcB,
                                             (__attribute__((address_space(3))) void*)dstB, 16, 0, 0);
        }
    };
    auto COMPUTE = [&](int buf) {
#pragma unroll
        for (int kk = 0; kk < 64; kk += 32) {
            bf16x8 af[4], bfr[4];
#pragma unroll
            for (int m = 0; m < 4; ++m) {
                int r  = waveM * 64 + m * 16 + frow;
                int kb_ = ((kk + fk) >> 3) ^ (r & 7);
                af[m] = *(const bf16x8*)&As[buf][r * 64 + kb_ * 8];
            }
#pragma unroll
            for (int n = 0; n < 4; ++n) {
                int r  = waveN * 64 + n * 16 + frow;
                int kb_ = ((kk + fk) >> 3) ^ (r & 7);
                bfr[n] = *(const bf16x8*)&Bs[buf][r * 64 + kb_ * 8];
            }
#pragma unroll
            for (int m = 0; m < 4; ++m)
#pragma unroll
                for (int n = 0; n < 4; ++n)
                    acc[m][n] = __builtin_amdgcn_mfma_f32_16x16x32_bf16(af[m], bfr[n], acc[m][n], 0, 0, 0);
        }
    };

    const int nk = K >> 6;                 // 32
    STAGE(0, 0);
    int buf = 0;
    for (int t = 0; t < nk - 1; ++t) {
        STAGE(buf ^ 1, (t + 1) << 6);      // next tile's 8 loads go in flight
        asm volatile("s_waitcnt vmcnt(8)" ::: "memory");  // own STAGE(t) landed
        __builtin_amdgcn_s_barrier();      // all waves' STAGE(t) landed
        __builtin_amdgcn_sched_barrier(0);
        COMPUTE(buf);
        __builtin_amdgcn_sched_barrier(0);
        __builtin_amdgcn_s_barrier();      // all waves done reading buf
        buf ^= 1;
    }
    asm volatile("s_waitcnt vmcnt(0)" ::: "memory");
    __builtin_amdgcn_s_barrier();
    __builtin_amdgcn_sched_barrier(0);
    COMPUTE(buf);

    const int rb = tm + waveM * 64;
    const int cb = tn + waveN * 64;
    const int s  = lane & 15;
    if (MODE == 0) {
#pragma unroll
        for (int m = 0; m < 4; ++m)
#pragma unroll
            for (int n = 0; n < 4; ++n)
#pragma unroll
                for (int r = 0; r < 4; ++r) {
                    int row = rb + m * 16 + (lane >> 4) * 4 + r;
                    int col = cb + n * 16 + s;
                    ((float*)Cout)[(size_t)row * N + col] = acc[m][n][r];
                }
    } else if (tn < 2048) {
        // Q tile: fused RoPE (pair exchange across adjacent lanes) -> qb
#pragma unroll
        for (int m = 0; m < 4; ++m)
#pragma unroll
            for (int n = 0; n < 4; ++n)
#pragma unroll
                for (int r = 0; r < 4; ++r) {
                    int row = rb + m * 16 + (lane >> 4) * 4 + r;
                    int col = cb + n * 16 + s;
                    float val  = acc[m][n][r];
                    float part = __shfl_xor(val, 1);
                    int i = (col & 127) >> 1;
                    const float* f4 = &fc[((size_t)row * 64 + i) * 4];
                    float cs = f4[0], sn = f4[2];
                    float q = (s & 1) ? (part * sn + val * cs)
                                      : (val * cs - part * sn);
                    qb[(size_t)row * 2048 + col] = f2b(q);
                }
    } else {
        // KV tile: bf16 -> c1kv (stride 1024)
#pragma unroll
        for (int m = 0; m < 4; ++m)
#pragma unroll
            for (int n = 0; n < 4; ++n)
#pragma unroll
                for (int r = 0; r < 4; ++r) {
                    int row = rb + m * 16 + (lane >> 4) * 4 + r;
                    int col = cb + n * 16 + s;
                    c1kv[(size_t)row * 1024 + (col - 2048)] = f2b(acc[m][n][r]);
                }
    }
}

// ---------------------------------------------------------------------------
// Kernel 2b: bf16 GEMM (output projection), 128x64 tile, 4 waves 64x32,
// 48KB LDS -> 3 blocks/CU. Counted-vmcnt 2-buffer (proven r10 config).
// ---------------------------------------------------------------------------
__global__ __launch_bounds__(256) void gemm_bt_kernel(
    const u16* __restrict__ A, const u16* __restrict__ B,
    float* __restrict__ Cout, int M, int N, int K)
{
    __shared__ u16 As[2][8192];   // 128 x 64
    __shared__ u16 Bs[2][4096];   //  64 x 64
    const int tid  = threadIdx.x;
    const int lane = tid & 63;
    const int wave = tid >> 6;
    const int waveM = wave >> 1, waveN = wave & 1;
    const int tm = blockIdx.y * 128;
    const int tn = blockIdx.x * 64;

    f32x4 acc[4][2];
#pragma unroll
    for (int i = 0; i < 4; ++i)
#pragma unroll
        for (int j = 0; j < 2; ++j) acc[i][j] = f32x4{0.f, 0.f, 0.f, 0.f};

    const int frow = lane & 15;
    const int fk   = (lane >> 4) * 8;

    auto STAGE = [&](int buf, int kt) {
#pragma unroll
        for (int c = 0; c < 4; ++c) {          // A: 1024 16B chunks
            int idx = c * 256 + tid;
            int row = idx >> 3;
            int blk = (idx & 7) ^ (row & 7);
            const u16* srcA = A + (size_t)(tm + row) * K + kt + blk * 8;
            u16* dstA = &As[buf][(size_t)(c * 256 + wave * 64) * 8];
            __builtin_amdgcn_global_load_lds((const __attribute__((address_space(1))) void*)srcA,
                                             (__attribute__((address_space(3))) void*)dstA, 16, 0, 0);
        }
#pragma unroll
        for (int c = 0; c < 2; ++c) {          // B: 512 16B chunks
            int idx = c * 256 + tid;
            int row = idx >> 3;
            int blk = (idx & 7) ^ (row & 7);
            const u16* srcB = B + (size_t)(tn + row) * K + kt + blk * 8;
            u16* dstB = &Bs[buf][(size_t)(c * 256 + wave * 64) * 8];
            __builtin_amdgcn_global_load_lds((const __attribute__((address_space(1))) void*)srcB,
                                             (__attribute__((address_space(3))) void*)dstB, 16, 0, 0);
        }
    };
    auto COMPUTE = [&](int buf) {
#pragma unroll
        for (int kk = 0; kk < 64; kk += 32) {
            bf16x8 af[4], bfr[2];
#pragma unroll
            for (int m = 0; m < 4; ++m) {
                int r  = waveM * 64 + m * 16 + frow;
                int kb_ = ((kk + fk) >> 3) ^ (r & 7);
                af[m] = *(const bf16x8*)&As[buf][r * 64 + kb_ * 8];
            }
#pragma unroll
            for (int n = 0; n < 2; ++n) {
                int r  = waveN * 32 + n * 16 + frow;
                int kb_ = ((kk + fk) >> 3) ^ (r & 7);
                bfr[n] = *(const bf16x8*)&Bs[buf][r * 64 + kb_ * 8];
            }
#pragma unroll
            for (int m = 0; m < 4; ++m)
#pragma unroll
                for (int n = 0; n < 2; ++n)
                    acc[m][n] = __builtin_amdgcn_mfma_f32_16x16x32_bf16(af[m], bfr[n], acc[m][n], 0, 0, 0);
        }
    };

    const int nk = K >> 6;                 // 32
    STAGE(0, 0);
    int buf = 0;
    for (int t = 0; t < nk - 1; ++t) {
        STAGE(buf ^ 1, (t + 1) << 6);
        asm volatile("s_waitcnt vmcnt(6)" ::: "memory");
        __builtin_amdgcn_s_barrier();
        __builtin_amdgcn_sched_barrier(0);
        COMPUTE(buf);
        __builtin_amdgcn_sched_barrier(0);
        __builtin_amdgcn_s_barrier();
        buf ^= 1;
    }
    asm volatile("s_waitcnt vmcnt(0)" ::: "memory");
    __builtin_amdgcn_s_barrier();
    __builtin_amdgcn_sched_barrier(0);
    COMPUTE(buf);

    const int rb = tm + waveM * 64;
    const int cb = tn + waveN * 32;
#pragma unroll
    for (int m = 0; m < 4; ++m)
#pragma unroll
        for (int n = 0; n < 2; ++n)
#pragma unroll
            for (int r = 0; r < 4; ++r) {
                int row = rb + m * 16 + (lane >> 4) * 4 + r;
                int col = cb + n * 16 + (lane & 15);
                Cout[(size_t)row * N + col] = acc[m][n][r];
            }
}

// ---------------------------------------------------------------------------
// Kernel 3: K/V SSM (chunk-8 scan) + residual (+RoPE for K), with fused
// boundary compaction: at tt==7 also write kbc[kvh][j][d] / vbt[kvh][d][j].
// ---------------------------------------------------------------------------
__global__ void ssm_kv_kernel(const u16* __restrict__ c1kv, const float* __restrict__ fc,
                              const float* __restrict__ alk, const float* __restrict__ bk,
                              const float* __restrict__ ck,
                              const float* __restrict__ alv, const float* __restrict__ bv,
                              const float* __restrict__ cv,
                              u16* __restrict__ kb, u16* __restrict__ vb,
                              u16* __restrict__ kbc, u16* __restrict__ vbt)
{
    int gi = blockIdx.x * 256 + threadIdx.x;
    if (gi < 65536) {
        int chunk = gi >> 8, pr = gi & 255;
        int i = pr & 63;
        int e0 = (pr >> 6) * 128 + 2 * i;         // channel in [0,512)
        float z0 = alk[e0], z1 = alk[e0 + 1];
        float sp0 = z0 > 20.f ? z0 : log1pf(__expf(z0));
        float sp1 = z1 > 20.f ? z1 : log1pf(__expf(z1));
        float a0 = __expf(-sp0), a1 = __expf(-sp1);
        float b0 = bk[e0], b1 = bk[e0 + 1];
        float c0 = ck[e0], cc1 = ck[e0 + 1];
        float h0 = 0.f, h1 = 0.f;
        int kvh = e0 >> 7, d = e0 & 127;
#pragma unroll
        for (int tt = 0; tt < 8; ++tt) {
            int sr = chunk * 8 + tt;
            u32 u = *(const u32*)&c1kv[(size_t)sr * 1024 + e0];
            float x0 = b2f((u16)(u & 0xffff)), x1 = b2f((u16)(u >> 16));
            h0 = a0 * h0 + b0 * x0;
            h1 = a1 * h1 + b1 * x1;
            float y0 = c0 * h0 + x0;
            float y1 = cc1 * h1 + x1;
            const float* f4 = &fc[((size_t)sr * 64 + i) * 4];
            float k0 = y0 * f4[0] - y1 * f4[2];
            float k1 = y0 * f4[2] + y1 * f4[0];
            u32 pk = (u32)f2b(k0) | ((u32)f2b(k1) << 16);
            *(u32*)&kb[(size_t)sr * 512 + e0] = pk;
            if (tt == 7)
                *(u32*)&kbc[(size_t)kvh * 32768 + chunk * 128 + d] = pk;
        }
    } else {
        int vi = gi - 65536;                       // [0,131072)
        int chunk = vi >> 9, e = vi & 511;
        float z = alv[e];
        float sp = z > 20.f ? z : log1pf(__expf(z));
        float a = __expf(-sp);
        float b = bv[e], c = cv[e];
        float h = 0.f;
#pragma unroll
        for (int tt = 0; tt < 8; ++tt) {
            int sr = chunk * 8 + tt;
            float xvv = b2f(c1kv[(size_t)sr * 1024 + 512 + e]);
            h = a * h + b * xvv;
            u16 y = f2b(c * h + xvv);
            vb[(size_t)sr * 512 + e] = y;
            if (tt == 7)
                vbt[((size_t)e << 8) + chunk] = y;   // (kvh<<7)+d == e
        }
    }
}

// ---------------------------------------------------------------------------
// Kernel 4: MFMA sparse attention, LDS-resident K/V (unchanged)
// ---------------------------------------------------------------------------
__global__ __launch_bounds__(512, 2) void attn_kernel(
    const u16* __restrict__ qb, const u16* __restrict__ kb, const u16* __restrict__ vb,
    const u16* __restrict__ kbc, const u16* __restrict__ vbt, u16* __restrict__ aout)
{
    __shared__ u16   ksbuf[32768];        // 64KB: K tile, then P buffer
    __shared__ u16   vsbuf[32768];        // 64KB: V^T tile
    __shared__ float p_ext[8][16][32];    // 16KB: extra-col P

    const int tid  = threadIdx.x;
    const int w    = tid >> 6;
    const int lane = tid & 63;
    const int s    = lane & 15;     // frag col / A-row
    const int g    = lane >> 4;     // k-group
    const int h    = blockIdx.x >> 4;
    const int t0   = (blockIdx.x & 15) * 128;
    const int kvh  = h >> 2;
    const int qw   = t0 + w * 16;   // wave's first query

    {
        const u16* kcb = kbc + ((size_t)kvh << 15);
#pragma unroll
        for (int it = 0; it < 8; ++it) {
            int idx = it * 512 + tid;
            int r = idx >> 4, b = idx & 15;
            const u16* src = kcb + r * 128 + ((b ^ (r & 7)) << 3);
            u16* dst = ksbuf + (size_t)(it * 512 + w * 64) * 8;
            __builtin_amdgcn_global_load_lds((const __attribute__((address_space(1))) void*)src,
                                             (__attribute__((address_space(3))) void*)dst, 16, 0, 0);
        }
    }
    __syncthreads();

    {
        const u16* vtb = vbt + ((size_t)kvh << 15);
#pragma unroll
        for (int it = 0; it < 8; ++it) {
            int idx = it * 512 + tid;
            int r = idx >> 5, b = idx & 31;
            const u16* src = vtb + r * 256 + ((b ^ (r & 7)) << 3);
            u16* dst = vsbuf + (size_t)(it * 512 + w * 64) * 8;
            __builtin_amdgcn_global_load_lds((const __attribute__((address_space(1))) void*)src,
                                             (__attribute__((address_space(3))) void*)dst, 16, 0, 0);
        }
    }

    bf16x8 qa[4];
    {
        const u16* qr = qb + (size_t)(qw + s) * 2048 + h * 128 + g * 8;
#pragma unroll
        for (int kk = 0; kk < 4; ++kk) qa[kk] = *(const bf16x8*)&qr[kk * 32];
    }

    f32x4 sf[18];
#pragma unroll
    for (int i = 0; i < 18; ++i) sf[i] = f32x4{0.f, 0.f, 0.f, 0.f};

#pragma unroll
    for (int fb = 0; fb < 16; ++fb) {
        int row = fb * 16 + s;
#pragma unroll
        for (int kk = 0; kk < 4; ++kk) {
            int ch = (kk * 4 + g) ^ (s & 7);
            bf16x8 bf = *(const bf16x8*)&ksbuf[row * 128 + ch * 8];
            sf[fb] = __builtin_amdgcn_mfma_f32_16x16x32_bf16(qa[kk], bf, sf[fb], 0, 0, 0);
        }
    }
#pragma unroll
    for (int xb = 0; xb < 2; ++xb) {
        int i = xb * 16 + s;
        int keyrow = (i < 4) ? i : (qw + (i - 4) - 1);
        if (keyrow < 0) keyrow = 0;
        if (keyrow > 2047) keyrow = 2047;
        const u16* kr = kb + (size_t)keyrow * 512 + kvh * 128 + g * 8;
#pragma unroll
        for (int kk = 0; kk < 4; ++kk) {
            bf16x8 bf = *(const bf16x8*)&kr[kk * 32];
            sf[16 + xb] = __builtin_amdgcn_mfma_f32_16x16x32_bf16(qa[kk], bf, sf[16 + xb], 0, 0, 0);
        }
    }

    const float scale = 0.08838834764831845f;  // 1/sqrt(128)
    float mx[4] = {-1e30f, -1e30f, -1e30f, -1e30f};
#pragma unroll
    for (int fi = 0; fi < 18; ++fi)
#pragma unroll
        for (int r = 0; r < 4; ++r) {
            int q = g * 4 + r;
            int t = qw + q;
            bool ok;
            if (fi < 16) {
                int j = fi * 16 + s;
                ok = j < (t >> 3);
            } else {
                int i = (fi - 16) * 16 + s;
                if (i < 4) ok = (i <= t);
                else       ok = ((i - 4) == q) && ((t & 7) != 0) && (t >= 5);
            }
            float v = ok ? sf[fi][r] * scale : -1e30f;
            sf[fi][r] = v;
            mx[r] = fmaxf(mx[r], v);
        }
#pragma unroll
    for (int r = 0; r < 4; ++r)
#pragma unroll
        for (int off = 8; off; off >>= 1) mx[r] = fmaxf(mx[r], __shfl_xor(mx[r], off));

    float sm[4] = {0.f, 0.f, 0.f, 0.f};
#pragma unroll
    for (int fi = 0; fi < 18; ++fi)
#pragma unroll
        for (int r = 0; r < 4; ++r) {
            float p = __expf(sf[fi][r] - mx[r]);
            sf[fi][r] = p;
            sm[r] += p;
        }
#pragma unroll
    for (int r = 0; r < 4; ++r)
#pragma unroll
        for (int off = 8; off; off >>= 1) sm[r] += __shfl_xor(sm[r], off);
    float inv[4];
#pragma unroll
    for (int r = 0; r < 4; ++r) inv[r] = 1.f / sm[r];

    __syncthreads();

    u16* pbuf = ksbuf + w * 4096;
#pragma unroll
    for (int fi = 0; fi < 16; ++fi)
#pragma unroll
        for (int r = 0; r < 4; ++r) {
            int q = g * 4 + r;
            int c = fi * 16 + s;
            int blk = (c >> 3) ^ q;
            pbuf[q * 256 + (blk << 3) + (c & 7)] = f2b(sf[fi][r]);
        }
#pragma unroll
    for (int xb = 0; xb < 2; ++xb)
#pragma unroll
        for (int r = 0; r < 4; ++r)
            p_ext[w][g * 4 + r][xb * 16 + s] = sf[16 + xb][r];

    bf16x8 pa[8];
#pragma unroll
    for (int kk = 0; kk < 8; ++kk) {
        int blk = (kk * 4 + g) ^ s;
        pa[kk] = *(const bf16x8*)&pbuf[s * 256 + (blk << 3)];
    }
    f32x4 out[8];
#pragma unroll
    for (int f = 0; f < 8; ++f) out[f] = f32x4{0.f, 0.f, 0.f, 0.f};
#pragma unroll
    for (int f = 0; f < 8; ++f) {
        int row = f * 16 + s;
#pragma unroll
        for (int kk = 0; kk < 8; ++kk) {
            int ch = (kk * 4 + g) ^ (s & 7);
            bf16x8 vf = *(const bf16x8*)&vsbuf[row * 256 + ch * 8];
            out[f] = __builtin_amdgcn_mfma_f32_16x16x32_bf16(pa[kk], vf, out[f], 0, 0, 0);
        }
    }

    {
        float v4[4][8];
#pragma unroll
        for (int e = 0; e < 4; ++e)
#pragma unroll
            for (int f = 0; f < 8; ++f)
                v4[e][f] = b2f(vb[(size_t)e * 512 + kvh * 128 + f * 16 + s]);
#pragma unroll
        for (int r = 0; r < 4; ++r) {
            int q = g * 4 + r;
            int t = qw + q;
#pragma unroll
            for (int e = 0; e < 4; ++e) {
                float p = p_ext[w][q][e];
#pragma unroll
                for (int f = 0; f < 8; ++f) out[f][r] += p * v4[e][f];
            }
            float pp = p_ext[w][q][4 + q];
            int key = t - 1; if (key < 0) key = 0;
            const u16* vr = vb + (size_t)key * 512 + kvh * 128;
#pragma unroll
            for (int f = 0; f < 8; ++f) out[f][r] += pp * b2f(vr[f * 16 + s]);
        }
    }

#pragma unroll
    for (int f = 0; f < 8; ++f)
#pragma unroll
        for (int r = 0; r < 4; ++r) {
            int t = qw + g * 4 + r;
            aout[(size_t)t * 2048 + h * 128 + f * 16 + s] = f2b(out[f][r] * inv[r]);
        }
}

// ---------------------------------------------------------------------------
extern "C" void kernel_launch(void* const* d_in, const int* in_sizes, int n_in,
                              void* d_out, int out_size, void* d_ws, size_t ws_size,
                              hipStream_t stream) {
    const float* x   = (const float*)d_in[0];
    const float* fc  = (const float*)d_in[1];
    const float* wq  = (const float*)d_in[2];
    const float* wk  = (const float*)d_in[3];
    const float* wv  = (const float*)d_in[4];
    const float* wo  = (const float*)d_in[5];
    const float* alk = (const float*)d_in[6];
    const float* bk  = (const float*)d_in[7];
    const float* ck  = (const float*)d_in[8];
    const float* alv = (const float*)d_in[9];
    const float* bv  = (const float*)d_in[10];
    const float* cv  = (const float*)d_in[11];

    char* ws = (char*)d_ws;
    u16*   xb   = (u16*)(ws);                  //  8,388,608 B
    u16*   wcat = (u16*)(ws + 8388608);        // 12,582,912 B
    u16*   wob  = (u16*)(ws + 20971520);       //  8,388,608 B
    u16*   c1kv = (u16*)(ws + 29360128);       //  4,194,304 B (bf16 KV only)
    u16*   qb   = (u16*)(ws + 54525952);       //  8,388,608 B
    u16*   kb   = (u16*)(ws + 62914560);       //  2,097,152 B
    u16*   vb   = (u16*)(ws + 65011712);       //  2,097,152 B
    u16*   kbc  = (u16*)(ws + 67108864);       //    262,144 B
    u16*   vbt  = (u16*)(ws + 67371008);       //    262,144 B
    u16*   aout = (u16*)(ws + 67633152);       //  8,388,608 B

    convert_kernel<<<14336, 256, 0, stream>>>(x, wq, wk, wv, wo, xb, wcat, wob);

    dim3 g1(3072 / 128, 2048 / 128);
    gemm_bt128_kernel<1><<<g1, 256, 0, stream>>>(xb, wcat, nullptr, 2048, 3072, 2048,
                                                 qb, c1kv, fc);

    ssm_kv_kernel<<<768, 256, 0, stream>>>(c1kv, fc, alk, bk, ck, alv, bv, cv,
                                           kb, vb, kbc, vbt);

    attn_kernel<<<256, 512, 0, stream>>>(qb, kb, vb, kbc, vbt, aout);

    dim3 g3(2048 / 64, 2048 / 128);
    gemm_bt_kernel<<<g3, 256, 0, stream>>>(aout, wob, (float*)d_out, 2048, 2048, 2048);
}

// Round 15
// 102.102 us; speedup vs baseline: 1.0788x; 1.0788x over previous
//
#include <hip/hip_runtime.h>

typedef __bf16 bf16x8 __attribute__((ext_vector_type(8)));
typedef float  f32x4  __attribute__((ext_vector_type(4)));
typedef unsigned short u16;
typedef unsigned int   u32;

__device__ __forceinline__ float b2f(u16 u) {
    u32 x = ((u32)u) << 16;
    return __builtin_bit_cast(float, x);
}
__device__ __forceinline__ u16 f2b(float f) {
    u32 x = __builtin_bit_cast(u32, f);
    x += 0x7fffu + ((x >> 16) & 1u);   // RNE
    return (u16)(x >> 16);
}

// ---------------------------------------------------------------------------
// Kernel 1: convert x, [wq;wk;wv], wo  f32 -> bf16  (vectorized x4)
// ---------------------------------------------------------------------------
__global__ void convert_kernel(const float* __restrict__ x, const float* __restrict__ wq,
                               const float* __restrict__ wk, const float* __restrict__ wv,
                               const float* __restrict__ wo,
                               u16* __restrict__ xb, u16* __restrict__ wcat, u16* __restrict__ wob)
{
    long i4 = (long)blockIdx.x * 256 + threadIdx.x;   // 0..3670015
    long e = i4 * 4;
    const float* src; u16* dst;
    if (e < 4194304) { src = x + e; dst = xb + e; }
    else if (e < 10485760) {
        long j = e - 4194304;
        dst = wcat + j;
        if (j < 4194304)      src = wq + j;
        else if (j < 5242880) src = wk + (j - 4194304);
        else                  src = wv + (j - 5242880);
    } else {
        long j = e - 10485760;
        src = wo + j; dst = wob + j;
    }
    float4 v = *(const float4*)src;
    uint2 pk;
    pk.x = (u32)f2b(v.x) | ((u32)f2b(v.y) << 16);
    pk.y = (u32)f2b(v.z) | ((u32)f2b(v.w) << 16);
    *(uint2*)dst = pk;
}

// ---------------------------------------------------------------------------
// Kernel 2a: bf16 GEMM (QKV projection, MODE-1 epilogue). r13-proven config:
// 128x64 tile, BK=64, 256 threads = 4 waves (2M x 2N), wave = 64x32 out.
// 48KB LDS -> 3 blocks/CU. Depth-1 counted-vmcnt 2-buffer.
// ---------------------------------------------------------------------------
__global__ __launch_bounds__(256) void gemm_qkv_kernel(
    const u16* __restrict__ A, const u16* __restrict__ B,
    int M, int N, int K,
    u16* __restrict__ qb, u16* __restrict__ c1kv, const float* __restrict__ fc)
{
    __shared__ u16 As[2][8192];   // 128 x 64
    __shared__ u16 Bs[2][4096];   //  64 x 64
    const int tid  = threadIdx.x;
    const int lane = tid & 63;
    const int wave = tid >> 6;
    const int waveM = wave >> 1, waveN = wave & 1;
    const int tm = blockIdx.y * 128;
    const int tn = blockIdx.x * 64;

    f32x4 acc[4][2];
#pragma unroll
    for (int i = 0; i < 4; ++i)
#pragma unroll
        for (int j = 0; j < 2; ++j) acc[i][j] = f32x4{0.f, 0.f, 0.f, 0.f};

    const int frow = lane & 15;
    const int fk   = (lane >> 4) * 8;

    auto STAGE = [&](int buf, int kt) {
#pragma unroll
        for (int c = 0; c < 4; ++c) {          // A: 1024 16B chunks
            int idx = c * 256 + tid;
            int row = idx >> 3;
            int blk = (idx & 7) ^ (row & 7);
            const u16* srcA = A + (size_t)(tm + row) * K + kt + blk * 8;
            u16* dstA = &As[buf][(size_t)(c * 256 + wave * 64) * 8];
            __builtin_amdgcn_global_load_lds((const __attribute__((address_space(1))) void*)srcA,
                                             (__attribute__((address_space(3))) void*)dstA, 16, 0, 0);
        }
#pragma unroll
        for (int c = 0; c < 2; ++c) {          // B: 512 16B chunks
            int idx = c * 256 + tid;
            int row = idx >> 3;
            int blk = (idx & 7) ^ (row & 7);
            const u16* srcB = B + (size_t)(tn + row) * K + kt + blk * 8;
            u16* dstB = &Bs[buf][(size_t)(c * 256 + wave * 64) * 8];
            __builtin_amdgcn_global_load_lds((const __attribute__((address_space(1))) void*)srcB,
                                             (__attribute__((address_space(3))) void*)dstB, 16, 0, 0);
        }
    };
    auto COMPUTE = [&](int buf) {
#pragma unroll
        for (int kk = 0; kk < 64; kk += 32) {
            bf16x8 af[4], bfr[2];
#pragma unroll
            for (int m = 0; m < 4; ++m) {
                int r  = waveM * 64 + m * 16 + frow;
                int kb_ = ((kk + fk) >> 3) ^ (r & 7);
                af[m] = *(const bf16x8*)&As[buf][r * 64 + kb_ * 8];
            }
#pragma unroll
            for (int n = 0; n < 2; ++n) {
                int r  = waveN * 32 + n * 16 + frow;
                int kb_ = ((kk + fk) >> 3) ^ (r & 7);
                bfr[n] = *(const bf16x8*)&Bs[buf][r * 64 + kb_ * 8];
            }
#pragma unroll
            for (int m = 0; m < 4; ++m)
#pragma unroll
                for (int n = 0; n < 2; ++n)
                    acc[m][n] = __builtin_amdgcn_mfma_f32_16x16x32_bf16(af[m], bfr[n], acc[m][n], 0, 0, 0);
        }
    };

    const int nk = K >> 6;                 // 32
    STAGE(0, 0);
    int buf = 0;
    for (int t = 0; t < nk - 1; ++t) {
        STAGE(buf ^ 1, (t + 1) << 6);      // next tile's 6 loads go in flight
        asm volatile("s_waitcnt vmcnt(6)" ::: "memory");  // own STAGE(t) landed
        __builtin_amdgcn_s_barrier();
        __builtin_amdgcn_sched_barrier(0);
        COMPUTE(buf);
        __builtin_amdgcn_sched_barrier(0);
        __builtin_amdgcn_s_barrier();
        buf ^= 1;
    }
    asm volatile("s_waitcnt vmcnt(0)" ::: "memory");
    __builtin_amdgcn_s_barrier();
    __builtin_amdgcn_sched_barrier(0);
    COMPUTE(buf);

    const int rb = tm + waveM * 64;
    const int cb = tn + waveN * 32;
    const int s  = lane & 15;
    if (tn < 2048) {
        // Q tile: fused RoPE (pair exchange across adjacent lanes) -> qb
#pragma unroll
        for (int m = 0; m < 4; ++m)
#pragma unroll
            for (int n = 0; n < 2; ++n)
#pragma unroll
                for (int r = 0; r < 4; ++r) {
                    int row = rb + m * 16 + (lane >> 4) * 4 + r;
                    int col = cb + n * 16 + s;
                    float val  = acc[m][n][r];
                    float part = __shfl_xor(val, 1);
                    int i = (col & 127) >> 1;
                    const float* f4 = &fc[((size_t)row * 64 + i) * 4];
                    float cs = f4[0], sn = f4[2];
                    float q = (s & 1) ? (part * sn + val * cs)
                                      : (val * cs - part * sn);
                    qb[(size_t)row * 2048 + col] = f2b(q);
                }
    } else {
        // KV tile: bf16 -> c1kv (stride 1024)
#pragma unroll
        for (int m = 0; m < 4; ++m)
#pragma unroll
            for (int n = 0; n < 2; ++n)
#pragma unroll
                for (int r = 0; r < 4; ++r) {
                    int row = rb + m * 16 + (lane >> 4) * 4 + r;
                    int col = cb + n * 16 + s;
                    c1kv[(size_t)row * 1024 + (col - 2048)] = f2b(acc[m][n][r]);
                }
    }
}

// ---------------------------------------------------------------------------
// Kernel 2b: bf16 GEMM (output projection), DEPTH-2 prefetch treatment:
// same 128x64 tile / 4 waves 64x32, but 3 LDS buffers (72KB -> 2 blocks/CU,
// which the 512-block grid supplies anyway). Per step:
//   { vmcnt(6): own STAGE(t) landed (t+1,t+2 in flight); s_barrier;
//     STAGE((t+2)%3); COMPUTE(t%3) }  — ONE barrier per K-step.
// Rotation safety: STAGE into (t+2)%3 == (t-1)%3 happens after the barrier
// that proves every wave finished COMPUTE(t-1) (its ds_reads were consumed
// by MFMAs before the wave could reach this barrier).
// ---------------------------------------------------------------------------
__global__ __launch_bounds__(256) void gemm_out_kernel(
    const u16* __restrict__ A, const u16* __restrict__ B,
    float* __restrict__ Cout, int M, int N, int K)
{
    __shared__ u16 As[3][8192];   // 3 x (128 x 64)
    __shared__ u16 Bs[3][4096];   // 3 x ( 64 x 64)
    const int tid  = threadIdx.x;
    const int lane = tid & 63;
    const int wave = tid >> 6;
    const int waveM = wave >> 1, waveN = wave & 1;
    const int tm = blockIdx.y * 128;
    const int tn = blockIdx.x * 64;

    f32x4 acc[4][2];
#pragma unroll
    for (int i = 0; i < 4; ++i)
#pragma unroll
        for (int j = 0; j < 2; ++j) acc[i][j] = f32x4{0.f, 0.f, 0.f, 0.f};

    const int frow = lane & 15;
    const int fk   = (lane >> 4) * 8;

    auto STAGE = [&](int buf, int kt) {
#pragma unroll
        for (int c = 0; c < 4; ++c) {          // A: 1024 16B chunks
            int idx = c * 256 + tid;
            int row = idx >> 3;
            int blk = (idx & 7) ^ (row & 7);
            const u16* srcA = A + (size_t)(tm + row) * K + kt + blk * 8;
            u16* dstA = &As[buf][(size_t)(c * 256 + wave * 64) * 8];
            __builtin_amdgcn_global_load_lds((const __attribute__((address_space(1))) void*)srcA,
                                             (__attribute__((address_space(3))) void*)dstA, 16, 0, 0);
        }
#pragma unroll
        for (int c = 0; c < 2; ++c) {          // B: 512 16B chunks
            int idx = c * 256 + tid;
            int row = idx >> 3;
            int blk = (idx & 7) ^ (row & 7);
            const u16* srcB = B + (size_t)(tn + row) * K + kt + blk * 8;
            u16* dstB = &Bs[buf][(size_t)(c * 256 + wave * 64) * 8];
            __builtin_amdgcn_global_load_lds((const __attribute__((address_space(1))) void*)srcB,
                                             (__attribute__((address_space(3))) void*)dstB, 16, 0, 0);
        }
    };
    auto COMPUTE = [&](int buf) {
#pragma unroll
        for (int kk = 0; kk < 64; kk += 32) {
            bf16x8 af[4], bfr[2];
#pragma unroll
            for (int m = 0; m < 4; ++m) {
                int r  = waveM * 64 + m * 16 + frow;
                int kb_ = ((kk + fk) >> 3) ^ (r & 7);
                af[m] = *(const bf16x8*)&As[buf][r * 64 + kb_ * 8];
            }
#pragma unroll
            for (int n = 0; n < 2; ++n) {
                int r  = waveN * 32 + n * 16 + frow;
                int kb_ = ((kk + fk) >> 3) ^ (r & 7);
                bfr[n] = *(const bf16x8*)&Bs[buf][r * 64 + kb_ * 8];
            }
#pragma unroll
            for (int m = 0; m < 4; ++m)
#pragma unroll
                for (int n = 0; n < 2; ++n)
                    acc[m][n] = __builtin_amdgcn_mfma_f32_16x16x32_bf16(af[m], bfr[n], acc[m][n], 0, 0, 0);
        }
    };

    const int nk = K >> 6;                 // 32
    STAGE(0, 0);
    STAGE(1, 64);
    for (int t = 0; t < nk - 2; ++t) {
        asm volatile("s_waitcnt vmcnt(6)" ::: "memory");  // STAGE(t) done; t+1 in flight
        __builtin_amdgcn_s_barrier();                     // all waves: buf t ready, compute(t-1) done
        __builtin_amdgcn_sched_barrier(0);
        STAGE((t + 2) % 3, (t + 2) << 6);                 // 2 compute phases to land
        COMPUTE(t % 3);
        __builtin_amdgcn_sched_barrier(0);
    }
    asm volatile("s_waitcnt vmcnt(6)" ::: "memory");      // STAGE(nk-2) done
    __builtin_amdgcn_s_barrier();
    __builtin_amdgcn_sched_barrier(0);
    COMPUTE((nk - 2) % 3);
    asm volatile("s_waitcnt vmcnt(0)" ::: "memory");      // STAGE(nk-1) done
    __builtin_amdgcn_s_barrier();
    __builtin_amdgcn_sched_barrier(0);
    COMPUTE((nk - 1) % 3);

    const int rb = tm + waveM * 64;
    const int cb = tn + waveN * 32;
#pragma unroll
    for (int m = 0; m < 4; ++m)
#pragma unroll
        for (int n = 0; n < 2; ++n)
#pragma unroll
            for (int r = 0; r < 4; ++r) {
                int row = rb + m * 16 + (lane >> 4) * 4 + r;
                int col = cb + n * 16 + (lane & 15);
                Cout[(size_t)row * N + col] = acc[m][n][r];
            }
}

// ---------------------------------------------------------------------------
// Kernel 3: K/V SSM (chunk-8 scan) + residual (+RoPE for K), with fused
// boundary compaction: at tt==7 also write kbc[kvh][j][d] / vbt[kvh][d][j].
// ---------------------------------------------------------------------------
__global__ void ssm_kv_kernel(const u16* __restrict__ c1kv, const float* __restrict__ fc,
                              const float* __restrict__ alk, const float* __restrict__ bk,
                              const float* __restrict__ ck,
                              const float* __restrict__ alv, const float* __restrict__ bv,
                              const float* __restrict__ cv,
                              u16* __restrict__ kb, u16* __restrict__ vb,
                              u16* __restrict__ kbc, u16* __restrict__ vbt)
{
    int gi = blockIdx.x * 256 + threadIdx.x;
    if (gi < 65536) {
        int chunk = gi >> 8, pr = gi & 255;
        int i = pr & 63;
        int e0 = (pr >> 6) * 128 + 2 * i;         // channel in [0,512)
        float z0 = alk[e0], z1 = alk[e0 + 1];
        float sp0 = z0 > 20.f ? z0 : log1pf(__expf(z0));
        float sp1 = z1 > 20.f ? z1 : log1pf(__expf(z1));
        float a0 = __expf(-sp0), a1 = __expf(-sp1);
        float b0 = bk[e0], b1 = bk[e0 + 1];
        float c0 = ck[e0], cc1 = ck[e0 + 1];
        float h0 = 0.f, h1 = 0.f;
        int kvh = e0 >> 7, d = e0 & 127;
#pragma unroll
        for (int tt = 0; tt < 8; ++tt) {
            int sr = chunk * 8 + tt;
            u32 u = *(const u32*)&c1kv[(size_t)sr * 1024 + e0];
            float x0 = b2f((u16)(u & 0xffff)), x1 = b2f((u16)(u >> 16));
            h0 = a0 * h0 + b0 * x0;
            h1 = a1 * h1 + b1 * x1;
            float y0 = c0 * h0 + x0;
            float y1 = cc1 * h1 + x1;
            const float* f4 = &fc[((size_t)sr * 64 + i) * 4];
            float k0 = y0 * f4[0] - y1 * f4[2];
            float k1 = y0 * f4[2] + y1 * f4[0];
            u32 pk = (u32)f2b(k0) | ((u32)f2b(k1) << 16);
            *(u32*)&kb[(size_t)sr * 512 + e0] = pk;
            if (tt == 7)
                *(u32*)&kbc[(size_t)kvh * 32768 + chunk * 128 + d] = pk;
        }
    } else {
        int vi = gi - 65536;                       // [0,131072)
        int chunk = vi >> 9, e = vi & 511;
        float z = alv[e];
        float sp = z > 20.f ? z : log1pf(__expf(z));
        float a = __expf(-sp);
        float b = bv[e], c = cv[e];
        float h = 0.f;
#pragma unroll
        for (int tt = 0; tt < 8; ++tt) {
            int sr = chunk * 8 + tt;
            float xvv = b2f(c1kv[(size_t)sr * 1024 + 512 + e]);
            h = a * h + b * xvv;
            u16 y = f2b(c * h + xvv);
            vb[(size_t)sr * 512 + e] = y;
            if (tt == 7)
                vbt[((size_t)e << 8) + chunk] = y;   // (kvh<<7)+d == e
        }
    }
}

// ---------------------------------------------------------------------------
// Kernel 4: MFMA sparse attention, LDS-resident K/V (unchanged)
// ---------------------------------------------------------------------------
__global__ __launch_bounds__(512, 2) void attn_kernel(
    const u16* __restrict__ qb, const u16* __restrict__ kb, const u16* __restrict__ vb,
    const u16* __restrict__ kbc, const u16* __restrict__ vbt, u16* __restrict__ aout)
{
    __shared__ u16   ksbuf[32768];        // 64KB: K tile, then P buffer
    __shared__ u16   vsbuf[32768];        // 64KB: V^T tile
    __shared__ float p_ext[8][16][32];    // 16KB: extra-col P

    const int tid  = threadIdx.x;
    const int w    = tid >> 6;
    const int lane = tid & 63;
    const int s    = lane & 15;     // frag col / A-row
    const int g    = lane >> 4;     // k-group
    const int h    = blockIdx.x >> 4;
    const int t0   = (blockIdx.x & 15) * 128;
    const int kvh  = h >> 2;
    const int qw   = t0 + w * 16;   // wave's first query

    {
        const u16* kcb = kbc + ((size_t)kvh << 15);
#pragma unroll
        for (int it = 0; it < 8; ++it) {
            int idx = it * 512 + tid;
            int r = idx >> 4, b = idx & 15;
            const u16* src = kcb + r * 128 + ((b ^ (r & 7)) << 3);
            u16* dst = ksbuf + (size_t)(it * 512 + w * 64) * 8;
            __builtin_amdgcn_global_load_lds((const __attribute__((address_space(1))) void*)src,
                                             (__attribute__((address_space(3))) void*)dst, 16, 0, 0);
        }
    }
    __syncthreads();

    {
        const u16* vtb = vbt + ((size_t)kvh << 15);
#pragma unroll
        for (int it = 0; it < 8; ++it) {
            int idx = it * 512 + tid;
            int r = idx >> 5, b = idx & 31;
            const u16* src = vtb + r * 256 + ((b ^ (r & 7)) << 3);
            u16* dst = vsbuf + (size_t)(it * 512 + w * 64) * 8;
            __builtin_amdgcn_global_load_lds((const __attribute__((address_space(1))) void*)src,
                                             (__attribute__((address_space(3))) void*)dst, 16, 0, 0);
        }
    }

    bf16x8 qa[4];
    {
        const u16* qr = qb + (size_t)(qw + s) * 2048 + h * 128 + g * 8;
#pragma unroll
        for (int kk = 0; kk < 4; ++kk) qa[kk] = *(const bf16x8*)&qr[kk * 32];
    }

    f32x4 sf[18];
#pragma unroll
    for (int i = 0; i < 18; ++i) sf[i] = f32x4{0.f, 0.f, 0.f, 0.f};

#pragma unroll
    for (int fb = 0; fb < 16; ++fb) {
        int row = fb * 16 + s;
#pragma unroll
        for (int kk = 0; kk < 4; ++kk) {
            int ch = (kk * 4 + g) ^ (s & 7);
            bf16x8 bf = *(const bf16x8*)&ksbuf[row * 128 + ch * 8];
            sf[fb] = __builtin_amdgcn_mfma_f32_16x16x32_bf16(qa[kk], bf, sf[fb], 0, 0, 0);
        }
    }
#pragma unroll
    for (int xb = 0; xb < 2; ++xb) {
        int i = xb * 16 + s;
        int keyrow = (i < 4) ? i : (qw + (i - 4) - 1);
        if (keyrow < 0) keyrow = 0;
        if (keyrow > 2047) keyrow = 2047;
        const u16* kr = kb + (size_t)keyrow * 512 + kvh * 128 + g * 8;
#pragma unroll
        for (int kk = 0; kk < 4; ++kk) {
            bf16x8 bf = *(const bf16x8*)&kr[kk * 32];
            sf[16 + xb] = __builtin_amdgcn_mfma_f32_16x16x32_bf16(qa[kk], bf, sf[16 + xb], 0, 0, 0);
        }
    }

    const float scale = 0.08838834764831845f;  // 1/sqrt(128)
    float mx[4] = {-1e30f, -1e30f, -1e30f, -1e30f};
#pragma unroll
    for (int fi = 0; fi < 18; ++fi)
#pragma unroll
        for (int r = 0; r < 4; ++r) {
            int q = g * 4 + r;
            int t = qw + q;
            bool ok;
            if (fi < 16) {
                int j = fi * 16 + s;
                ok = j < (t >> 3);
            } else {
                int i = (fi - 16) * 16 + s;
                if (i < 4) ok = (i <= t);
                else       ok = ((i - 4) == q) && ((t & 7) != 0) && (t >= 5);
            }
            float v = ok ? sf[fi][r] * scale : -1e30f;
            sf[fi][r] = v;
            mx[r] = fmaxf(mx[r], v);
        }
#pragma unroll
    for (int r = 0; r < 4; ++r)
#pragma unroll
        for (int off = 8; off; off >>= 1) mx[r] = fmaxf(mx[r], __shfl_xor(mx[r], off));

    float sm[4] = {0.f, 0.f, 0.f, 0.f};
#pragma unroll
    for (int fi = 0; fi < 18; ++fi)
#pragma unroll
        for (int r = 0; r < 4; ++r) {
            float p = __expf(sf[fi][r] - mx[r]);
            sf[fi][r] = p;
            sm[r] += p;
        }
#pragma unroll
    for (int r = 0; r < 4; ++r)
#pragma unroll
        for (int off = 8; off; off >>= 1) sm[r] += __shfl_xor(sm[r], off);
    float inv[4];
#pragma unroll
    for (int r = 0; r < 4; ++r) inv[r] = 1.f / sm[r];

    __syncthreads();

    u16* pbuf = ksbuf + w * 4096;
#pragma unroll
    for (int fi = 0; fi < 16; ++fi)
#pragma unroll
        for (int r = 0; r < 4; ++r) {
            int q = g * 4 + r;
            int c = fi * 16 + s;
            int blk = (c >> 3) ^ q;
            pbuf[q * 256 + (blk << 3) + (c & 7)] = f2b(sf[fi][r]);
        }
#pragma unroll
    for (int xb = 0; xb < 2; ++xb)
#pragma unroll
        for (int r = 0; r < 4; ++r)
            p_ext[w][g * 4 + r][xb * 16 + s] = sf[16 + xb][r];

    bf16x8 pa[8];
#pragma unroll
    for (int kk = 0; kk < 8; ++kk) {
        int blk = (kk * 4 + g) ^ s;
        pa[kk] = *(const bf16x8*)&pbuf[s * 256 + (blk << 3)];
    }
    f32x4 out[8];
#pragma unroll
    for (int f = 0; f < 8; ++f) out[f] = f32x4{0.f, 0.f, 0.f, 0.f};
#pragma unroll
    for (int f = 0; f < 8; ++f) {
        int row = f * 16 + s;
#pragma unroll
        for (int kk = 0; kk < 8; ++kk) {
            int ch = (kk * 4 + g) ^ (s & 7);
            bf16x8 vf = *(const bf16x8*)&vsbuf[row * 256 + ch * 8];
            out[f] = __builtin_amdgcn_mfma_f32_16x16x32_bf16(pa[kk], vf, out[f], 0, 0, 0);
        }
    }

    {
        float v4[4][8];
#pragma unroll
        for (int e = 0; e < 4; ++e)
#pragma unroll
            for (int f = 0; f < 8; ++f)
                v4[e][f] = b2f(vb[(size_t)e * 512 + kvh * 128 + f * 16 + s]);
#pragma unroll
        for (int r = 0; r < 4; ++r) {
            int q = g * 4 + r;
            int t = qw + q;
#pragma unroll
            for (int e = 0; e < 4; ++e) {
                float p = p_ext[w][q][e];
#pragma unroll
                for (int f = 0; f < 8; ++f) out[f][r] += p * v4[e][f];
            }
            float pp = p_ext[w][q][4 + q];
            int key = t - 1; if (key < 0) key = 0;
            const u16* vr = vb + (size_t)key * 512 + kvh * 128;
#pragma unroll
            for (int f = 0; f < 8; ++f) out[f][r] += pp * b2f(vr[f * 16 + s]);
        }
    }

#pragma unroll
    for (int f = 0; f < 8; ++f)
#pragma unroll
        for (int r = 0; r < 4; ++r) {
            int t = qw + g * 4 + r;
            aout[(size_t)t * 2048 + h * 128 + f * 16 + s] = f2b(out[f][r] * inv[r]);
        }
}

// ---------------------------------------------------------------------------
extern "C" void kernel_launch(void* const* d_in, const int* in_sizes, int n_in,
                              void* d_out, int out_size, void* d_ws, size_t ws_size,
                              hipStream_t stream) {
    const float* x   = (const float*)d_in[0];
    const float* fc  = (const float*)d_in[1];
    const float* wq  = (const float*)d_in[2];
    const float* wk  = (const float*)d_in[3];
    const float* wv  = (const float*)d_in[4];
    const float* wo  = (const float*)d_in[5];
    const float* alk = (const float*)d_in[6];
    const float* bk  = (const float*)d_in[7];
    const float* ck  = (const float*)d_in[8];
    const float* alv = (const float*)d_in[9];
    const float* bv  = (const float*)d_in[10];
    const float* cv  = (const float*)d_in[11];

    char* ws = (char*)d_ws;
    u16*   xb   = (u16*)(ws);                  //  8,388,608 B
    u16*   wcat = (u16*)(ws + 8388608);        // 12,582,912 B
    u16*   wob  = (u16*)(ws + 20971520);       //  8,388,608 B
    u16*   c1kv = (u16*)(ws + 29360128);       //  4,194,304 B (bf16 KV only)
    u16*   qb   = (u16*)(ws + 54525952);       //  8,388,608 B
    u16*   kb   = (u16*)(ws + 62914560);       //  2,097,152 B
    u16*   vb   = (u16*)(ws + 65011712);       //  2,097,152 B
    u16*   kbc  = (u16*)(ws + 67108864);       //    262,144 B
    u16*   vbt  = (u16*)(ws + 67371008);       //    262,144 B
    u16*   aout = (u16*)(ws + 67633152);       //  8,388,608 B

    convert_kernel<<<14336, 256, 0, stream>>>(x, wq, wk, wv, wo, xb, wcat, wob);

    dim3 g1(3072 / 64, 2048 / 128);
    gemm_qkv_kernel<<<g1, 256, 0, stream>>>(xb, wcat, 2048, 3072, 2048,
                                            qb, c1kv, fc);

    ssm_kv_kernel<<<768, 256, 0, stream>>>(c1kv, fc, alk, bk, ck, alv, bv, cv,
                                           kb, vb, kbc, vbt);

    attn_kernel<<<256, 512, 0, stream>>>(qb, kb, vb, kbc, vbt, aout);

    dim3 g3(2048 / 64, 2048 / 128);
    gemm_out_kernel<<<g3, 256, 0, stream>>>(aout, wob, (float*)d_out, 2048, 2048, 2048);
}